// Round 6
// baseline (7099.393 us; speedup 1.0000x reference)
//
#include <hip/hip_runtime.h>
#include <hip/hip_bf16.h>

// ContTimeLSTM: L=512, B=32, DIN=512, H=1024.
// Persistent kernel: 64 WGs x 512 threads (8 waves, 2/SIMD).
// WG g owns h-columns [16g, 16g+16) => 96 projection rows.
// Waves 0-5: gate g rows (16 each, B in 192 VGPRs). Wave 6: d-row. Wave 7: spare.
// x: double-buffered bf16 LDS tile. h: staged once/WG via coalesced sc1
// dwordx4 loads into swizzled LDS. Packed ushort epoch flags (1 cache line
// region) for the per-step device-wide sync; all cross-WG data via sc1.

#define L_STEPS 512
#define BATCH   32
#define DIN     512
#define HDIM    1024
#define KDIM    1536
#define NWG     64
#define CPW     16
#define NTHREADS 512

// LDS layout (bytes)
#define LDS_XB0   0                      // [32][512] bf16 swizzled (32 KB)
#define LDS_XB1   32768
#define LDS_HB    65536                  // [32][1024] bf16 swizzled (64 KB)
#define LDS_PROJ  131072                 // 96*33 floats = 12672 B
#define LDS_DLS   143744                 // 32 floats
#define LDS_HSTG  143872                 // 32*16 bf16 = 1024 B
#define LDS_BYTES 144896

#define WS_FLAGS_BYTES 1024              // 64 ushorts used

typedef __attribute__((ext_vector_type(8))) __bf16 bf16x8;
typedef __attribute__((ext_vector_type(4))) float  f32x4;
typedef __attribute__((ext_vector_type(4))) unsigned int u32x4;

__device__ __forceinline__ float fsigmoid(float u) { return 1.0f / (1.0f + __expf(-u)); }

__device__ __forceinline__ bf16x8 pack8(float4 fa, float4 fb) {
    bf16x8 v;
    v[0] = (__bf16)fa.x; v[1] = (__bf16)fa.y; v[2] = (__bf16)fa.z; v[3] = (__bf16)fa.w;
    v[4] = (__bf16)fb.x; v[5] = (__bf16)fb.y; v[6] = (__bf16)fb.z; v[7] = (__bf16)fb.w;
    return v;
}

extern "C" __global__ void __launch_bounds__(NTHREADS, 2)
ctlstm_kernel(const float* __restrict__ x,
              const float* __restrict__ tdel,
              const float* __restrict__ o_state,
              const float* __restrict__ cs_state,
              const float* __restrict__ ce_state,
              const float* __restrict__ d_state,
              const float* __restrict__ weight,
              const float* __restrict__ bias,
              const float* __restrict__ d_weight,
              const float* __restrict__ d_bias,
              const float* __restrict__ d_beta_p,
              float* __restrict__ out0,
              float* __restrict__ out1,
              unsigned short* __restrict__ flags,
              __bf16* __restrict__ h0,
              __bf16* __restrict__ h1)
{
    extern __shared__ char smem[];
    float*  proj = (float*)(smem + LDS_PROJ);
    float*  dls  = (float*)(smem + LDS_DLS);
    __bf16* hstg = (__bf16*)(smem + LDS_HSTG);
    char*   hbp  = smem + LDS_HB;

    const int tid = threadIdx.x;
    const int wg  = blockIdx.x;
    const int c0  = wg * CPW;

    const int wv = tid >> 6;       // 0..7
    const int l  = tid & 63;
    const int lr = l & 15;
    const int lk = l >> 4;

    // per-thread persistent state: (b, j), j in [0,16)
    const int b = tid >> 4, j = tid & 15;
    float s_o, s_cs, s_ce, dt_cur;
    {
        int gi = b * HDIM + c0 + j;
        s_o = o_state[gi]; s_cs = cs_state[gi]; s_ce = ce_state[gi];
        dt_cur = tdel[b];
    }
    if (tid < BATCH) dls[tid] = d_state[tid];

    // ---- startup: weights into registers ----
    bf16x8 Bx[16], Bh[32];
    float bias_r = 0.f;
    {
        const float* wsrc = nullptr;
        if (wv < 6) {
            wsrc = weight + (size_t)(wv * HDIM + c0 + lr) * KDIM;
            bias_r = bias[wv * HDIM + c0 + lr];
        } else if (wv == 6 && lr == 0) {
            wsrc = d_weight;
        }
        #pragma unroll
        for (int kc = 0; kc < 48; ++kc) {
            bf16x8 v = {};
            if (wsrc) {
                float4 fa = *(const float4*)(wsrc + kc * 32 + lk * 8);
                float4 fb = *(const float4*)(wsrc + kc * 32 + lk * 8 + 4);
                v = pack8(fa, fb);
            }
            if (kc < 16) Bx[kc] = v; else Bh[kc - 16] = v;
        }
    }
    const float dbias_s = d_bias[0];
    const float beta    = d_beta_p[0];

    // ---- startup: stage x panel 0 (bf16, swizzled) ----
    {
        const char* xp = (const char*)x + tid * 128;
        float4 x0[8];
        #pragma unroll
        for (int i = 0; i < 8; ++i) x0[i] = *(const float4*)(xp + i * 16);
        #pragma unroll
        for (int m = 0; m < 4; ++m) {
            int g = tid * 64 + m * 16;
            int bt = g >> 10, colb = g & 1023;
            unsigned ba = (unsigned)(bt * 1024) + ((unsigned)colb ^ (((unsigned)bt & 7) << 4));
            *(bf16x8*)(smem + LDS_XB0 + ba) = pack8(x0[2 * m], x0[2 * m + 1]);
        }
    }
    __syncthreads();

    for (int t = 0; t < L_STEPS; ++t) {
        __bf16* hcur = (t & 1) ? h1 : h0;
        char* xcur = smem + ((t & 1) ? LDS_XB1 : LDS_XB0);
        char* xnxt = smem + ((t & 1) ? LDS_XB0 : LDS_XB1);

        // ---- phase 1: c, h; stage h slice in LDS ----
        float dv = dls[b];
        float c  = s_cs + (s_ce - s_cs) * __expf(-dv * dt_cur);
        float h_reg = s_o * (1.f - 2.f / (__expf(2.f * c) + 1.f));  // o*tanh(c)
        float c_reg = c;
        hstg[b * CPW + j] = (__bf16)h_reg;
        __syncthreads();   // S1

        // ---- wave 0: publish 1 KB h slice (16-B sc1 stores), ack, flag ----
        if (tid < 64) {
            int bb = tid >> 1, half = tid & 1;
            u32x4 v = *(const u32x4*)((const char*)hstg + tid * 16);
            void* dst = (char*)hcur + (size_t)bb * 2048 + c0 * 2 + half * 16;
            asm volatile("global_store_dwordx4 %0, %1, off sc1" :: "v"(dst), "v"(v) : "memory");
            asm volatile("s_waitcnt vmcnt(0)" ::: "memory");
            if (tid == 0)
                __hip_atomic_store(flags + wg, (unsigned short)(t + 1),
                                   __ATOMIC_RELAXED, __HIP_MEMORY_SCOPE_AGENT);
            asm volatile("" ::: "memory");
        }

        // ---- off-path: out0, tdel prefetch, next x panel loads ----
        __builtin_nontemporal_store(h_reg, out0 + ((size_t)b * L_STEPS + t) * HDIM + c0 + j);
        int tn = (t + 1 < L_STEPS) ? t + 1 : t;
        float dt_nxt = tdel[tn * BATCH + b];
        float4 xr[8];
        {
            const char* xp = (const char*)(x + (size_t)tn * BATCH * DIN) + tid * 128;
            #pragma unroll
            for (int i = 0; i < 8; ++i) xr[i] = *(const float4*)(xp + i * 16);
        }

        // ---- x-part MFMA (overlaps barrier window) ----
        f32x4 acc0 = {0.f, 0.f, 0.f, 0.f};
        f32x4 acc1 = {0.f, 0.f, 0.f, 0.f};
        if (wv < 7) {
            const unsigned swz = ((unsigned)(lr & 7)) << 4;
            #pragma unroll
            for (int kc = 0; kc < 16; ++kc) {
                unsigned cb = (unsigned)(kc * 64 + lk * 16);
                bf16x8 a0 = *(const bf16x8*)(xcur + lr * 1024 + (cb ^ swz));
                bf16x8 a1 = *(const bf16x8*)(xcur + (16 + lr) * 1024 + (cb ^ swz));
                acc0 = __builtin_amdgcn_mfma_f32_16x16x32_bf16(a0, Bx[kc], acc0, 0, 0, 0);
                acc1 = __builtin_amdgcn_mfma_f32_16x16x32_bf16(a1, Bx[kc], acc1, 0, 0, 0);
            }
        }

        // ---- convert + write next x panel ----
        #pragma unroll
        for (int m = 0; m < 4; ++m) {
            int g = tid * 64 + m * 16;
            int bt = g >> 10, colb = g & 1023;
            unsigned ba = (unsigned)(bt * 1024) + ((unsigned)colb ^ (((unsigned)bt & 7) << 4));
            *(bf16x8*)(xnxt + ba) = pack8(xr[2 * m], xr[2 * m + 1]);
        }

        // ---- poll: all 64 WGs published (all waves poll 1 line) ----
        {
            const unsigned tgt = (unsigned)(t + 1);
            const unsigned* fl = (const unsigned*)flags + (l & 31);
            for (;;) {
                unsigned v = __hip_atomic_load(fl, __ATOMIC_RELAXED, __HIP_MEMORY_SCOPE_AGENT);
                if (__all((int)((v & 0xFFFFu) >= tgt && (v >> 16) >= tgt))) break;
            }
        }

        // ---- stage h: 8 x 16-B coalesced sc1 loads/thread -> swizzled LDS ----
        {
            const char* hsrc = (const char*)hcur + tid * 128;
            u32x4 q[8];
            #pragma unroll
            for (int i = 0; i < 8; ++i) {
                const void* p = hsrc + i * 16;
                asm volatile("global_load_dwordx4 %0, %1, off sc1"
                             : "=v"(q[i]) : "v"(p) : "memory");
            }
            asm volatile("s_waitcnt vmcnt(0)" ::: "memory");
            #pragma unroll
            for (int i = 0; i < 8; ++i) {
                int g = tid * 128 + i * 16;
                int bt = g >> 11, colb = g & 2047;
                unsigned ba = (unsigned)(bt * 2048) + ((unsigned)colb ^ (((unsigned)bt & 7) << 4));
                *(u32x4*)(hbp + ba) = q[i];
            }
        }
        __syncthreads();   // S_stage

        // ---- h-part MFMA ----
        if (wv < 7) {
            const unsigned swz = ((unsigned)(lr & 7)) << 4;
            #pragma unroll
            for (int kc = 0; kc < 32; ++kc) {
                unsigned cb = (unsigned)(kc * 64 + lk * 16);
                bf16x8 a0 = *(const bf16x8*)(hbp + lr * 2048 + (cb ^ swz));
                bf16x8 a1 = *(const bf16x8*)(hbp + (16 + lr) * 2048 + (cb ^ swz));
                acc0 = __builtin_amdgcn_mfma_f32_16x16x32_bf16(a0, Bh[kc], acc0, 0, 0, 0);
                acc1 = __builtin_amdgcn_mfma_f32_16x16x32_bf16(a1, Bh[kc], acc1, 0, 0, 0);
            }
            if (wv < 6) {
                const int n = wv * 16 + lr;
                #pragma unroll
                for (int r = 0; r < 4; ++r) {
                    proj[n * 33 + lk * 4 + r]      = fsigmoid(acc0[r] + bias_r);
                    proj[n * 33 + 16 + lk * 4 + r] = fsigmoid(acc1[r] + bias_r);
                }
            } else if (lr == 0) {
                #pragma unroll
                for (int r = 0; r < 4; ++r) {
                    int b0 = lk * 4 + r, b1 = 16 + lk * 4 + r;
                    float bu0 = beta * (acc0[r] + dbias_s);
                    float bu1 = beta * (acc1[r] + dbias_s);
                    float sp0 = fmaxf(bu0, 0.f) + __logf(1.f + __expf(-fabsf(bu0)));
                    float sp1 = fmaxf(bu1, 0.f) + __logf(1.f + __expf(-fabsf(bu1)));
                    float dn0 = sp0 / beta, dn1 = sp1 / beta;
                    dls[b0] = dn0; dls[b1] = dn1;
                    if (wg == 0) {
                        __builtin_nontemporal_store(dn0, out1 + ((size_t)b0 * L_STEPS + t) * 3073 + 3072);
                        __builtin_nontemporal_store(dn1, out1 + ((size_t)b1 * L_STEPS + t) * 3073 + 3072);
                    }
                }
            }
        }
        __syncthreads();   // S3

        // ---- epilogue: gate algebra, state update, outputs (64-B lines) ----
        {
            float gi  = proj[(0 * 16 + j) * 33 + b];
            float gf  = proj[(1 * 16 + j) * 33 + b];
            float gie = proj[(2 * 16 + j) * 33 + b];
            float gfe = proj[(3 * 16 + j) * 33 + b];
            float gz  = proj[(4 * 16 + j) * 33 + b];
            float go  = proj[(5 * 16 + j) * 33 + b];
            float z   = 2.f * gz - 1.f;
            float csn = gf * c_reg + gi * z;
            float cen = gfe * s_ce + gie * z;
            size_t ob = ((size_t)b * L_STEPS + t) * 3073;
            __builtin_nontemporal_store(go,  out1 + ob + c0 + j);
            __builtin_nontemporal_store(csn, out1 + ob + HDIM + c0 + j);
            __builtin_nontemporal_store(cen, out1 + ob + 2 * HDIM + c0 + j);
            s_o = go; s_cs = csn; s_ce = cen;
        }
        dt_cur = dt_nxt;
    }
}

extern "C" void kernel_launch(void* const* d_in, const int* in_sizes, int n_in,
                              void* d_out, int out_size, void* d_ws, size_t ws_size,
                              hipStream_t stream) {
    const float* x        = (const float*)d_in[0];
    const float* tdel     = (const float*)d_in[1];
    const float* o_state  = (const float*)d_in[2];
    const float* cs_state = (const float*)d_in[3];
    const float* ce_state = (const float*)d_in[4];
    const float* d_state  = (const float*)d_in[5];
    const float* weight   = (const float*)d_in[6];
    const float* bias     = (const float*)d_in[7];
    const float* d_weight = (const float*)d_in[8];
    const float* d_bias   = (const float*)d_in[9];
    const float* d_beta   = (const float*)d_in[10];

    float* out0 = (float*)d_out;
    float* out1 = out0 + (size_t)BATCH * L_STEPS * HDIM;

    unsigned short* flags = (unsigned short*)d_ws;
    __bf16* h0 = (__bf16*)((char*)d_ws + WS_FLAGS_BYTES);
    __bf16* h1 = (__bf16*)((char*)d_ws + WS_FLAGS_BYTES + (size_t)BATCH * HDIM * 2);

    (void)hipMemsetAsync(d_ws, 0, WS_FLAGS_BYTES, stream);  // re-arm flags every launch
    (void)hipFuncSetAttribute((const void*)ctlstm_kernel,
                              hipFuncAttributeMaxDynamicSharedMemorySize, LDS_BYTES);
    ctlstm_kernel<<<NWG, NTHREADS, LDS_BYTES, stream>>>(
        x, tdel, o_state, cs_state, ce_state, d_state,
        weight, bias, d_weight, d_bias, d_beta,
        out0, out1, flags, h0, h1);
}